// Round 13
// baseline (74.895 us; speedup 1.0000x reference)
//
#include <hip/hip_runtime.h>

#define Nn 4096
#define NTRI 528              // 32*33/2 upper-tri 128x128 tiles
#define NBLK 2080             // 2*528 + 1024

typedef __attribute__((ext_vector_type(4))) float f32x4;
typedef __attribute__((ext_vector_type(2))) long  long2v;

#define C_K   0.7213475204444817f   // log2(e)/mu, mu=2
#define C_2K  1.4426950408889634f   // 2*log2(e)/mu
#define SKIP_BOUND -40.0f           // exp2(-40)*16.7M*beta ~ 1e-19 << 1e-5 threshold

// manual f32 -> fp8 e4m3fn (RNE, FTZ below 2^-6, saturate to 448)
__device__ __forceinline__ unsigned f2e4m3(float f) {
  unsigned u = __float_as_uint(f);
  unsigned s = (u >> 24) & 0x80u;
  int e = (int)((u >> 23) & 0xff);
  unsigned m = u & 0x7fffffu;
  if (e < 121) return s;                         // FTZ (|x| < 2^-6), incl. zero
  unsigned mr = m + 0x7ffffu + ((m >> 20) & 1u); // RNE to 3 mantissa bits
  if (mr & 0x800000u) { mr = 0; e += 1; }
  int code = ((e - 120) << 3) | (int)(mr >> 20);
  if (code > 0x7e) code = 0x7e;                  // clamp to 448 (no inf/nan)
  return s | (unsigned)code;
}

__device__ __forceinline__ void gload_lds16(const void* g, void* l) {
  __builtin_amdgcn_global_load_lds(
      (const __attribute__((address_space(1))) unsigned int*)g,
      (__attribute__((address_space(3))) unsigned int*)l, 16, 0, 0);
}

// ---- prep: fp8 cast into FRAGMENT-NATIVE layout + norms (verified r11/r12) ---
// Row r, byte k: panel p=r>>4, c=k>>6, L=((k>>3)&3)*16+(r&15), half=(k>>5)&1:
//   offset = p*2048 + c*1024 + L*16 + half*8 + (k&7)
__global__ __launch_bounds__(256) void prep_kernel(const float* __restrict__ X,
                                                   const float* __restrict__ Y,
                                                   float* __restrict__ kn,
                                                   unsigned char* __restrict__ Xf,
                                                   unsigned char* __restrict__ Yf) {
  int wave = threadIdx.x >> 6;
  int lane = threadIdx.x & 63;
  int row = blockIdx.x * 4 + wave;            // 0..8191
  const float* src;
  unsigned char* dstm;
  int r;
  if (row < Nn) { r = row;      src = X + (size_t)r * 128; dstm = Xf; }
  else          { r = row - Nn; src = Y + (size_t)r * 128; dstm = Yf; }
  float2 v = reinterpret_cast<const float2*>(src)[lane];
  float s = v.x * v.x + v.y * v.y;
#pragma unroll
  for (int off = 32; off > 0; off >>= 1) s += __shfl_xor(s, off);
  unsigned short h = (unsigned short)(f2e4m3(v.x) | (f2e4m3(v.y) << 8));
  const int c    = lane >> 5;
  const int half = (lane >> 4) & 1;
  const int kq   = (lane >> 2) & 3;
  const int L    = (kq << 4) + (r & 15);
  const size_t off8 = ((size_t)(r >> 4) << 11) + (c << 10) + (L << 4)
                    + (half << 3) + ((lane & 3) << 1);
  *reinterpret_cast<unsigned short*>(dstm + off8) = h;
  if (lane == 0) kn[row] = -C_K * s;
}

// ---- fused pairwise-exp-sum: 8-wave blocks, 16 waves/CU, last-block reduce ---
// t < 528:        q=0 (XX), upper-tri tile (by<=bx), off-diag weight 2
// 528 <= t <1056: q=1 (YY), same
// t >= 1056:      q=2 (XY), full 32x32
// Wave tile 64x32 (2x4 wave grid): acc = 8 f32x4 = 32 VGPR; peak regs ~100
// -> __launch_bounds__(512,4) (cap 128) = 16 waves/CU, 2x r11's TLP.
__global__ __launch_bounds__(512, 4) void mmd_main(const unsigned char* __restrict__ Xf,
                                                   const unsigned char* __restrict__ Yf,
                                                   const float* __restrict__ kn,
                                                   float* __restrict__ partials,
                                                   unsigned* __restrict__ cnt,
                                                   float* __restrict__ out) {
  __shared__ __align__(16) char As[16384];
  __shared__ __align__(16) char Bs[16384];
  __shared__ float red[8];
  __shared__ unsigned isLast;

  const int t = blockIdx.x;
  int q, bx, by;
  if (t < 2 * NTRI) {
    q = (t >= NTRI) ? 1 : 0;
    const int u = t - q * NTRI;
    int r = (int)((sqrtf(8.f * (float)u + 1.f) - 1.f) * 0.5f);
    while ((r + 1) * (r + 2) / 2 <= u) ++r;
    while (r * (r + 1) / 2 > u) --r;
    bx = r; by = u - r * (r + 1) / 2;          // by <= bx
  } else {
    q = 2;
    const int u = t - 2 * NTRI;
    by = u >> 5; bx = u & 31;
  }

  const unsigned char* Asrc = (q == 1) ? Yf : Xf;
  const unsigned char* Bsrc = (q == 0) ? Xf : Yf;
  const float* knA = (q == 1) ? kn + Nn : kn;
  const float* knB = (q == 0) ? kn : kn + Nn;
  const int R0 = by << 7, C0 = bx << 7;

  const int lane = threadIdx.x & 63;
  const int wv   = threadIdx.x >> 6;      // 0..7
  const int wr = wv >> 2, wc = wv & 3;    // 2x4 wave grid: 64 rows x 32 cols
  const int lr = lane & 15, kq = lane >> 4;

  // ---- stage: 2KB per wave per operand (2+2 gload_lds16) ---------------------
  {
    const char* Ag = (const char*)Asrc + ((size_t)by << 14) + (wv << 11) + (lane << 4);
    const char* Bg = (const char*)Bsrc + ((size_t)bx << 14) + (wv << 11) + (lane << 4);
    gload_lds16(Ag,        As + (wv << 11));
    gload_lds16(Ag + 1024, As + (wv << 11) + 1024);
    gload_lds16(Bg,        Bs + (wv << 11));
    gload_lds16(Bg + 1024, Bs + (wv << 11) + 1024);
  }
  __syncthreads();

  // ---- MFMA: per K-half, 6 linear ds_read_b128 + 16 MFMAs --------------------
  f32x4 acc[4][2];
#pragma unroll
  for (int i = 0; i < 4; ++i)
#pragma unroll
    for (int j = 0; j < 2; ++j)
      acc[i][j] = (f32x4){0.f, 0.f, 0.f, 0.f};

#pragma unroll
  for (int c = 0; c < 2; ++c) {
    long a0[4], a1[4], b0[2], b1[2];
#pragma unroll
    for (int i = 0; i < 4; ++i) {
      long2v ta = *reinterpret_cast<const long2v*>(
          As + ((((wr << 2) + i) << 11) + (c << 10) + (lane << 4)));
      a0[i] = ta[0]; a1[i] = ta[1];
    }
#pragma unroll
    for (int j = 0; j < 2; ++j) {
      long2v tb = *reinterpret_cast<const long2v*>(
          Bs + ((((wc << 1) + j) << 11) + (c << 10) + (lane << 4)));
      b0[j] = tb[0]; b1[j] = tb[1];
    }
#pragma unroll
    for (int i = 0; i < 4; ++i)
#pragma unroll
      for (int j = 0; j < 2; ++j)
        acc[i][j] = __builtin_amdgcn_mfma_f32_16x16x32_fp8_fp8(a0[i], b0[j], acc[i][j], 0, 0, 0);
#pragma unroll
    for (int i = 0; i < 4; ++i)
#pragma unroll
      for (int j = 0; j < 2; ++j)
        acc[i][j] = __builtin_amdgcn_mfma_f32_16x16x32_fp8_fp8(a1[i], b1[j], acc[i][j], 0, 0, 0);
  }

  // ---- epilogue: wave-level underflow skip, then exp2 -------------------------
  const bool diagblk = (q < 2) && (bx == by);
  f32x4 ax[4];
  float cy[2];
#pragma unroll
  for (int i = 0; i < 4; ++i)
    ax[i] = *reinterpret_cast<const f32x4*>(knA + R0 + (wr << 6) + (i << 4) + (kq << 2));
#pragma unroll
  for (int j = 0; j < 2; ++j)
    cy[j] = knB[C0 + (wc << 5) + (j << 4) + lr];

  f32x4 vm = acc[0][0];
#pragma unroll
  for (int i = 0; i < 4; ++i)
#pragma unroll
    for (int j = 0; j < 2; ++j) {
      if (i == 0 && j == 0) continue;
      vm[0] = fmaxf(vm[0], acc[i][j][0]);
      vm[1] = fmaxf(vm[1], acc[i][j][1]);
      vm[2] = fmaxf(vm[2], acc[i][j][2]);
      vm[3] = fmaxf(vm[3], acc[i][j][3]);
    }
  float amax = fmaxf(fmaxf(vm[0], vm[1]), fmaxf(vm[2], vm[3]));
  float axm = -1e30f;
#pragma unroll
  for (int i = 0; i < 4; ++i)
    axm = fmaxf(axm, fmaxf(fmaxf(ax[i][0], ax[i][1]), fmaxf(ax[i][2], ax[i][3])));
  float cym = fmaxf(cy[0], cy[1]);
  float bound = fmaf(amax, C_2K, axm + cym);

  float local = 0.f;
  if (__any(bound > SKIP_BOUND)) {
    float l0 = 0.f, l1 = 0.f, l2 = 0.f, l3 = 0.f;
#pragma unroll
    for (int i = 0; i < 4; ++i) {
      const int rbase = (wr << 6) + (i << 4) + (kq << 2);
#pragma unroll
      for (int j = 0; j < 2; ++j) {
        const float e0 = __builtin_amdgcn_exp2f(fmaf(acc[i][j][0], C_2K, ax[i][0] + cy[j]));
        const float e1 = __builtin_amdgcn_exp2f(fmaf(acc[i][j][1], C_2K, ax[i][1] + cy[j]));
        const float e2 = __builtin_amdgcn_exp2f(fmaf(acc[i][j][2], C_2K, ax[i][2] + cy[j]));
        const float e3 = __builtin_amdgcn_exp2f(fmaf(acc[i][j][3], C_2K, ax[i][3] + cy[j]));
        if (diagblk) {
          const int cc = (wc << 5) + (j << 4) + lr;
          if (rbase + 0 != cc) l0 += e0;
          if (rbase + 1 != cc) l1 += e1;
          if (rbase + 2 != cc) l2 += e2;
          if (rbase + 3 != cc) l3 += e3;
        } else {
          l0 += e0; l1 += e1; l2 += e2; l3 += e3;
        }
      }
    }
    local = (l0 + l1) + (l2 + l3);
#pragma unroll
    for (int off = 32; off > 0; off >>= 1) local += __shfl_xor(local, off);
  }

  if (lane == 0) red[wv] = local;
  __syncthreads();
  if (threadIdx.x == 0) {
    float s = ((red[0] + red[1]) + (red[2] + red[3]))
            + ((red[4] + red[5]) + (red[6] + red[7]));
    float w;
    if (q < 2) w = ((bx == by) ? 1.f : 2.f) * (1.0f / 16773120.0f);  // alpha
    else       w = -2.0f / 16777216.0f;                               // -2*beta
    __hip_atomic_store(&partials[t], s * w, __ATOMIC_RELEASE, __HIP_MEMORY_SCOPE_AGENT);
    unsigned old = __hip_atomic_fetch_add(cnt, 1u, __ATOMIC_ACQ_REL, __HIP_MEMORY_SCOPE_AGENT);
    isLast = (old == NBLK - 1) ? 1u : 0u;
  }
  __syncthreads();

  // ---- last block: deterministic final reduction (fixed order) ----------------
  if (isLast) {
    float v = 0.f;
    for (int i = threadIdx.x; i < NBLK; i += 512)
      v += __hip_atomic_load(&partials[i], __ATOMIC_ACQUIRE, __HIP_MEMORY_SCOPE_AGENT);
#pragma unroll
    for (int off = 32; off > 0; off >>= 1) v += __shfl_xor(v, off);
    if (lane == 0) red[wv] = v;
    __syncthreads();
    if (threadIdx.x == 0)
      out[0] = (((red[0] + red[1]) + (red[2] + red[3]))
              + ((red[4] + red[5]) + (red[6] + red[7]))) + (float)(2.0 / 4095.0);
  }
}

extern "C" void kernel_launch(void* const* d_in, const int* in_sizes, int n_in,
                              void* d_out, int out_size, void* d_ws, size_t ws_size,
                              hipStream_t stream) {
  const float* X = (const float*)d_in[0];
  const float* Y = (const float*)d_in[1];

  unsigned* cnt     = (unsigned*)d_ws;                    // 1 u32 (64B slot)
  float* kn         = (float*)d_ws + 16;                  // 8192 floats
  float* partials   = kn + 8192;                          // 2080 floats
  unsigned char* Xf = (unsigned char*)(partials + 2080);  // 512 KB fragment-native fp8
  unsigned char* Yf = Xf + (size_t)Nn * 128;              // 512 KB
  float* out = (float*)d_out;

  hipMemsetAsync(cnt, 0, 4, stream);   // reset ticket (graph-capture safe)
  hipLaunchKernelGGL(prep_kernel, dim3(2048), dim3(256), 0, stream, X, Y, kn, Xf, Yf);
  hipLaunchKernelGGL(mmd_main, dim3(NBLK), dim3(512), 0, stream,
                     Xf, Yf, kn, partials, cnt, out);
}

// Round 14
// 21.905 us; speedup vs baseline: 3.4191x; 3.4191x over previous
//
#include <hip/hip_runtime.h>

#define Nn 4096
#define NTRI 528              // 32*33/2 upper-tri 128x128 tiles
#define NBLK 2080             // 2*528 + 1024

typedef __attribute__((ext_vector_type(4))) float f32x4;
typedef __attribute__((ext_vector_type(2))) long  long2v;

#define C_K   0.7213475204444817f   // log2(e)/mu, mu=2
#define C_2K  1.4426950408889634f   // 2*log2(e)/mu
#define SKIP_BOUND -40.0f           // exp2(-40)*16.7M*beta ~ 1e-19 << 1e-5 threshold

// manual f32 -> fp8 e4m3fn (RNE, FTZ below 2^-6, saturate to 448)
__device__ __forceinline__ unsigned f2e4m3(float f) {
  unsigned u = __float_as_uint(f);
  unsigned s = (u >> 24) & 0x80u;
  int e = (int)((u >> 23) & 0xff);
  unsigned m = u & 0x7fffffu;
  if (e < 121) return s;                         // FTZ (|x| < 2^-6), incl. zero
  unsigned mr = m + 0x7ffffu + ((m >> 20) & 1u); // RNE to 3 mantissa bits
  if (mr & 0x800000u) { mr = 0; e += 1; }
  int code = ((e - 120) << 3) | (int)(mr >> 20);
  if (code > 0x7e) code = 0x7e;                  // clamp to 448 (no inf/nan)
  return s | (unsigned)code;
}

__device__ __forceinline__ void gload_lds16(const void* g, void* l) {
  __builtin_amdgcn_global_load_lds(
      (const __attribute__((address_space(1))) unsigned int*)g,
      (__attribute__((address_space(3))) unsigned int*)l, 16, 0, 0);
}

// ---- prep: fp8 cast into FRAGMENT-NATIVE layout + norms (verified r11-r13) ---
// Row r, byte k: panel p=r>>4, c=k>>6, L=((k>>3)&3)*16+(r&15), half=(k>>5)&1:
//   offset = p*2048 + c*1024 + L*16 + half*8 + (k&7)
__global__ __launch_bounds__(256) void prep_kernel(const float* __restrict__ X,
                                                   const float* __restrict__ Y,
                                                   float* __restrict__ kn,
                                                   unsigned char* __restrict__ Xf,
                                                   unsigned char* __restrict__ Yf) {
  int wave = threadIdx.x >> 6;
  int lane = threadIdx.x & 63;
  int row = blockIdx.x * 4 + wave;            // 0..8191
  const float* src;
  unsigned char* dstm;
  int r;
  if (row < Nn) { r = row;      src = X + (size_t)r * 128; dstm = Xf; }
  else          { r = row - Nn; src = Y + (size_t)r * 128; dstm = Yf; }
  float2 v = reinterpret_cast<const float2*>(src)[lane];
  float s = v.x * v.x + v.y * v.y;
#pragma unroll
  for (int off = 32; off > 0; off >>= 1) s += __shfl_xor(s, off);
  unsigned short h = (unsigned short)(f2e4m3(v.x) | (f2e4m3(v.y) << 8));
  const int c    = lane >> 5;
  const int half = (lane >> 4) & 1;
  const int kq   = (lane >> 2) & 3;
  const int L    = (kq << 4) + (r & 15);
  const size_t off8 = ((size_t)(r >> 4) << 11) + (c << 10) + (L << 4)
                    + (half << 3) + ((lane & 3) << 1);
  *reinterpret_cast<unsigned short*>(dstm + off8) = h;
  if (lane == 0) kn[row] = -C_K * s;
}

// ---- fused pairwise-exp-sum: 8 waves, 64x32 wave tile, 16 waves/CU -----------
// t < 528:        q=0 (XX), upper-tri tile (by<=bx), off-diag weight 2
// 528 <= t <1056: q=1 (YY), same
// t >= 1056:      q=2 (XY), full 32x32
// r13 PMC: VGPR=36(+32 AGPR), no spill, no conflicts at this shape; the 60us
// regression was the single-line device-scope atomics (removed here).
__global__ __launch_bounds__(512, 4) void mmd_main(const unsigned char* __restrict__ Xf,
                                                   const unsigned char* __restrict__ Yf,
                                                   const float* __restrict__ kn,
                                                   float* __restrict__ partials) {
  __shared__ __align__(16) char As[16384];
  __shared__ __align__(16) char Bs[16384];
  __shared__ float red[8];

  const int t = blockIdx.x;
  int q, bx, by;
  if (t < 2 * NTRI) {
    q = (t >= NTRI) ? 1 : 0;
    const int u = t - q * NTRI;
    int r = (int)((sqrtf(8.f * (float)u + 1.f) - 1.f) * 0.5f);
    while ((r + 1) * (r + 2) / 2 <= u) ++r;
    while (r * (r + 1) / 2 > u) --r;
    bx = r; by = u - r * (r + 1) / 2;          // by <= bx
  } else {
    q = 2;
    const int u = t - 2 * NTRI;
    by = u >> 5; bx = u & 31;
  }

  const unsigned char* Asrc = (q == 1) ? Yf : Xf;
  const unsigned char* Bsrc = (q == 0) ? Xf : Yf;
  const float* knA = (q == 1) ? kn + Nn : kn;
  const float* knB = (q == 0) ? kn : kn + Nn;
  const int R0 = by << 7, C0 = bx << 7;

  const int lane = threadIdx.x & 63;
  const int wv   = threadIdx.x >> 6;      // 0..7
  const int wr = wv >> 2, wc = wv & 3;    // 2x4 wave grid: 64 rows x 32 cols
  const int lr = lane & 15, kq = lane >> 4;

  // ---- stage: 2KB per wave per operand (2+2 gload_lds16) ---------------------
  {
    const char* Ag = (const char*)Asrc + ((size_t)by << 14) + (wv << 11) + (lane << 4);
    const char* Bg = (const char*)Bsrc + ((size_t)bx << 14) + (wv << 11) + (lane << 4);
    gload_lds16(Ag,        As + (wv << 11));
    gload_lds16(Ag + 1024, As + (wv << 11) + 1024);
    gload_lds16(Bg,        Bs + (wv << 11));
    gload_lds16(Bg + 1024, Bs + (wv << 11) + 1024);
  }
  __syncthreads();

  // ---- MFMA: per K-half, 6 linear ds_read_b128 + 16 MFMAs --------------------
  f32x4 acc[4][2];
#pragma unroll
  for (int i = 0; i < 4; ++i)
#pragma unroll
    for (int j = 0; j < 2; ++j)
      acc[i][j] = (f32x4){0.f, 0.f, 0.f, 0.f};

#pragma unroll
  for (int c = 0; c < 2; ++c) {
    long a0[4], a1[4], b0[2], b1[2];
#pragma unroll
    for (int i = 0; i < 4; ++i) {
      long2v ta = *reinterpret_cast<const long2v*>(
          As + ((((wr << 2) + i) << 11) + (c << 10) + (lane << 4)));
      a0[i] = ta[0]; a1[i] = ta[1];
    }
#pragma unroll
    for (int j = 0; j < 2; ++j) {
      long2v tb = *reinterpret_cast<const long2v*>(
          Bs + ((((wc << 1) + j) << 11) + (c << 10) + (lane << 4)));
      b0[j] = tb[0]; b1[j] = tb[1];
    }
#pragma unroll
    for (int i = 0; i < 4; ++i)
#pragma unroll
      for (int j = 0; j < 2; ++j)
        acc[i][j] = __builtin_amdgcn_mfma_f32_16x16x32_fp8_fp8(a0[i], b0[j], acc[i][j], 0, 0, 0);
#pragma unroll
    for (int i = 0; i < 4; ++i)
#pragma unroll
      for (int j = 0; j < 2; ++j)
        acc[i][j] = __builtin_amdgcn_mfma_f32_16x16x32_fp8_fp8(a1[i], b1[j], acc[i][j], 0, 0, 0);
  }

  // ---- epilogue: wave-level underflow skip, then exp2 -------------------------
  const bool diagblk = (q < 2) && (bx == by);
  f32x4 ax[4];
  float cy[2];
#pragma unroll
  for (int i = 0; i < 4; ++i)
    ax[i] = *reinterpret_cast<const f32x4*>(knA + R0 + (wr << 6) + (i << 4) + (kq << 2));
#pragma unroll
  for (int j = 0; j < 2; ++j)
    cy[j] = knB[C0 + (wc << 5) + (j << 4) + lr];

  f32x4 vm = acc[0][0];
#pragma unroll
  for (int i = 0; i < 4; ++i)
#pragma unroll
    for (int j = 0; j < 2; ++j) {
      if (i == 0 && j == 0) continue;
      vm[0] = fmaxf(vm[0], acc[i][j][0]);
      vm[1] = fmaxf(vm[1], acc[i][j][1]);
      vm[2] = fmaxf(vm[2], acc[i][j][2]);
      vm[3] = fmaxf(vm[3], acc[i][j][3]);
    }
  float amax = fmaxf(fmaxf(vm[0], vm[1]), fmaxf(vm[2], vm[3]));
  float axm = -1e30f;
#pragma unroll
  for (int i = 0; i < 4; ++i)
    axm = fmaxf(axm, fmaxf(fmaxf(ax[i][0], ax[i][1]), fmaxf(ax[i][2], ax[i][3])));
  float cym = fmaxf(cy[0], cy[1]);
  float bound = fmaf(amax, C_2K, axm + cym);

  float local = 0.f;
  if (__any(bound > SKIP_BOUND)) {
    float l0 = 0.f, l1 = 0.f, l2 = 0.f, l3 = 0.f;
#pragma unroll
    for (int i = 0; i < 4; ++i) {
      const int rbase = (wr << 6) + (i << 4) + (kq << 2);
#pragma unroll
      for (int j = 0; j < 2; ++j) {
        const float e0 = __builtin_amdgcn_exp2f(fmaf(acc[i][j][0], C_2K, ax[i][0] + cy[j]));
        const float e1 = __builtin_amdgcn_exp2f(fmaf(acc[i][j][1], C_2K, ax[i][1] + cy[j]));
        const float e2 = __builtin_amdgcn_exp2f(fmaf(acc[i][j][2], C_2K, ax[i][2] + cy[j]));
        const float e3 = __builtin_amdgcn_exp2f(fmaf(acc[i][j][3], C_2K, ax[i][3] + cy[j]));
        if (diagblk) {
          const int cc = (wc << 5) + (j << 4) + lr;
          if (rbase + 0 != cc) l0 += e0;
          if (rbase + 1 != cc) l1 += e1;
          if (rbase + 2 != cc) l2 += e2;
          if (rbase + 3 != cc) l3 += e3;
        } else {
          l0 += e0; l1 += e1; l2 += e2; l3 += e3;
        }
      }
    }
    local = (l0 + l1) + (l2 + l3);
#pragma unroll
    for (int off = 32; off > 0; off >>= 1) local += __shfl_xor(local, off);
  }

  if (lane == 0) red[wv] = local;
  __syncthreads();
  if (threadIdx.x == 0) {
    float s = ((red[0] + red[1]) + (red[2] + red[3]))
            + ((red[4] + red[5]) + (red[6] + red[7]));
    float w;
    if (q < 2) w = ((bx == by) ? 1.f : 2.f) * (1.0f / 16773120.0f);  // alpha
    else       w = -2.0f / 16777216.0f;                               // -2*beta
    partials[t] = s * w;                 // plain store; no device-scope atomics
  }
}

// ---- deterministic final reduction ------------------------------------------
__global__ __launch_bounds__(256) void mmd_final(const float* __restrict__ partials,
                                                 float* __restrict__ out) {
  float v = 0.f;
  for (int i = threadIdx.x; i < NBLK; i += 256) v += partials[i];
#pragma unroll
  for (int off = 32; off > 0; off >>= 1) v += __shfl_xor(v, off);
  __shared__ float red[4];
  if ((threadIdx.x & 63) == 0) red[threadIdx.x >> 6] = v;
  __syncthreads();
  if (threadIdx.x == 0) {
    // analytic diagonal: n*(alpha1+alpha2) = 2/4095
    out[0] = ((red[0] + red[1]) + (red[2] + red[3])) + (float)(2.0 / 4095.0);
  }
}

extern "C" void kernel_launch(void* const* d_in, const int* in_sizes, int n_in,
                              void* d_out, int out_size, void* d_ws, size_t ws_size,
                              hipStream_t stream) {
  const float* X = (const float*)d_in[0];
  const float* Y = (const float*)d_in[1];
  float* kn         = (float*)d_ws;                       // 8192 floats (-K*norm^2)
  float* partials   = kn + 8192;                          // 2080 floats
  unsigned char* Xf = (unsigned char*)(partials + 2080);  // 512 KB fragment-native fp8
  unsigned char* Yf = Xf + (size_t)Nn * 128;              // 512 KB
  float* out = (float*)d_out;

  hipLaunchKernelGGL(prep_kernel, dim3(2048), dim3(256), 0, stream, X, Y, kn, Xf, Yf);
  hipLaunchKernelGGL(mmd_main, dim3(NBLK), dim3(512), 0, stream, Xf, Yf, kn, partials);
  hipLaunchKernelGGL(mmd_final, dim3(1), dim3(256), 0, stream, partials, out);
}